// Round 1
// baseline (619.528 us; speedup 1.0000x reference)
//
#include <hip/hip_runtime.h>
#include <math.h>

#define BATCH 65536
#define EMBED 128
#define HIST 5
#define NEG 2
#define LPE 16   // lanes per element
#define DPL 8    // dims per lane (2 x float4)

struct Row { float4 a, b; };

__device__ __forceinline__ float sqd(const Row& p, const Row& q) {
    float d0 = p.a.x - q.a.x;
    float d1 = p.a.y - q.a.y;
    float d2 = p.a.z - q.a.z;
    float d3 = p.a.w - q.a.w;
    float d4 = p.b.x - q.b.x;
    float d5 = p.b.y - q.b.y;
    float d6 = p.b.z - q.b.z;
    float d7 = p.b.w - q.b.w;
    return d0*d0 + d1*d1 + d2*d2 + d3*d3 + d4*d4 + d5*d5 + d6*d6 + d7*d7;
}

__device__ __forceinline__ float logsig(float z) {
    // stable log_sigmoid: min(z,0) - log1p(exp(-|z|))
    return fminf(z, 0.0f) - log1pf(expf(-fabsf(z)));
}

__global__ __launch_bounds__(256) void htne_kernel(
    const int*   __restrict__ xs,
    const int*   __restrict__ ys,
    const float* __restrict__ e_times,
    const int*   __restrict__ hs,
    const float* __restrict__ h_times,
    const int*   __restrict__ neg,
    const float* __restrict__ mask,
    const float* __restrict__ emb,
    const float* __restrict__ delta_tab,
    float*       __restrict__ out)
{
    const int tid = blockIdx.x * blockDim.x + threadIdx.x;
    const int e   = tid >> 4;                 // element index (16 lanes/element)
    const int sub = threadIdx.x & (LPE - 1);  // lane within element group
    if (e >= BATCH) return;

    const float4* embv = (const float4*)emb;  // 32 float4 per row

    // --- gather row indices (same address across the 16-lane group -> broadcast)
    const int xrow = xs[e];
    const int yrow = ys[e];
    int hrow[HIST];
#pragma unroll
    for (int h = 0; h < HIST; ++h) hrow[h] = hs[e * HIST + h];
    int nrow[NEG];
#pragma unroll
    for (int n = 0; n < NEG; ++n) nrow[n] = neg[e * NEG + n];

    // --- issue all 18 float4-pair loads up front (MLP)
    const size_t co = (size_t)(sub * 2);  // float4 column offset within row
    Row x, y, h[HIST], nn[NEG];
    {
        const float4* p = embv + (size_t)xrow * 32 + co;
        x.a = p[0]; x.b = p[1];
    }
    {
        const float4* p = embv + (size_t)yrow * 32 + co;
        y.a = p[0]; y.b = p[1];
    }
#pragma unroll
    for (int i = 0; i < HIST; ++i) {
        const float4* p = embv + (size_t)hrow[i] * 32 + co;
        h[i].a = p[0]; h[i].b = p[1];
    }
#pragma unroll
    for (int i = 0; i < NEG; ++i) {
        const float4* p = embv + (size_t)nrow[i] * 32 + co;
        nn[i].a = p[0]; nn[i].b = p[1];
    }

    // --- 18 per-lane partial squared distances
    // r[0]            : ||x-y||^2
    // r[1..5]         : ||x-h_i||^2
    // r[6..7]         : ||x-n_j||^2
    // r[8 + i*2 + j]  : ||h_i-n_j||^2
    float r[18];
    r[0] = sqd(x, y);
#pragma unroll
    for (int i = 0; i < HIST; ++i) r[1 + i] = sqd(x, h[i]);
#pragma unroll
    for (int j = 0; j < NEG; ++j) r[6 + j] = sqd(x, nn[j]);
#pragma unroll
    for (int i = 0; i < HIST; ++i)
#pragma unroll
        for (int j = 0; j < NEG; ++j) r[8 + i * 2 + j] = sqd(h[i], nn[j]);

    // --- butterfly reduce across the 16-lane group (4 steps, serves 4 elems/wave)
#pragma unroll
    for (int i = 0; i < 18; ++i) {
#pragma unroll
        for (int m = 1; m < LPE; m <<= 1) {
            r[i] += __shfl_xor(r[i], m, 64);
        }
    }

    // --- scalar epilogue (all 16 lanes redundantly; no divergence)
    const float p_mu = -r[0];

    float alpha[HIST];
#pragma unroll
    for (int i = 0; i < HIST; ++i) alpha[i] = -r[1 + i];

    float mx = alpha[0];
#pragma unroll
    for (int i = 1; i < HIST; ++i) mx = fmaxf(mx, alpha[i]);

    float ex[HIST];
    float s = 0.0f;
#pragma unroll
    for (int i = 0; i < HIST; ++i) { ex[i] = expf(alpha[i] - mx); s += ex[i]; }
    const float inv_s = 1.0f / s;

    const float et    = e_times[e];
    const float delta = delta_tab[xrow];

    float w[HIST];
    float p_acc = 0.0f;
#pragma unroll
    for (int i = 0; i < HIST; ++i) {
        const float dt    = fabsf(et - h_times[e * HIST + i]);
        const float decay = expf(delta * dt) * mask[e * HIST + i];
        w[i] = ex[i] * inv_s * decay;   // attn * decay
        p_acc += w[i] * alpha[i];
    }
    const float p_lambda = p_mu + p_acc;

    float loss = logsig(p_lambda);
#pragma unroll
    for (int j = 0; j < NEG; ++j) {
        float nl = -r[6 + j];
#pragma unroll
        for (int i = 0; i < HIST; ++i) nl += w[i] * (-r[8 + i * 2 + j]);
        loss -= logsig(nl);
    }

    if (sub == 0) out[e] = loss;
}

extern "C" void kernel_launch(void* const* d_in, const int* in_sizes, int n_in,
                              void* d_out, int out_size, void* d_ws, size_t ws_size,
                              hipStream_t stream) {
    const int*   xs        = (const int*)  d_in[0];
    const int*   ys        = (const int*)  d_in[1];
    const float* e_times   = (const float*)d_in[2];
    const int*   hs        = (const int*)  d_in[3];
    const float* h_times   = (const float*)d_in[4];
    const int*   neg       = (const int*)  d_in[5];
    const float* mask      = (const float*)d_in[6];
    const float* emb       = (const float*)d_in[7];
    const float* delta_tab = (const float*)d_in[8];
    float*       out       = (float*)d_out;

    const int threads = 256;                    // 16 elements per block
    const int blocks  = (BATCH * LPE) / threads; // 4096
    htne_kernel<<<blocks, threads, 0, stream>>>(
        xs, ys, e_times, hs, h_times, neg, mask, emb, delta_tab, out);
}